// Round 7
// baseline (431.010 us; speedup 1.0000x reference)
//
#include <hip/hip_runtime.h>

#define NROWS 8192
#define NCOLS 8192
#define LDIM  8193          // matching_scores row stride
#define NBINS 64
#define KCORR 2048
#define MAXC  8192
#define CAP   192           // candidate bucket capacity per row (mean ~55, sd ~7)
// Fast cut: v <= exp(m)*1 <= 0.08 < t41 (~0.09). Bins 0..41 exact from the
// slow set alone; expected crossing n* ~ 33.
#define FCUT_LOG (-2.5257286443082556f)   // ln(0.08)

#define NQUAD   16781312    // floor(8193*8193/4); leftover elem = dustbin corner
#define TILEQ   1024        // quads per tile = 256 threads * 4
#define NTILES  16388       // NQUAD / TILEQ (exact)
#define NGROUPS 262208      // NQUAD / 64 (exact) = NTILES*16

__device__ __forceinline__ float inner_val(float m, float rr, float sc) {
    float p = rr * sc;
    return expf(m) * p;      // EXACTLY the reference expression
}

__device__ __forceinline__ void fold_thresholds(float* t) {
    float tv = 0.5f;
    for (int n = 0; n < NBINS; ++n) { t[n] = tv; tv = tv - 0.01f; }
}

// exact bin = #{n : t[n] >= v}: arithmetic guess + short verify walk
__device__ __forceinline__ int exact_bin(float v, const float* t) {
    int g = (int)floorf((0.5f - v) * 100.0f) + 1;
    g = (g < 0) ? 0 : ((g > NBINS) ? NBINS : g);
    while (g < NBINS && t[g] >= v) ++g;
    while (g > 0 && t[g - 1] < v) --g;
    return (g > 63) ? 63 : g;
}

__global__ void init_kernel(float* __restrict__ out, unsigned* __restrict__ hist,
                            unsigned* __restrict__ hist2,
                            unsigned* __restrict__ candcnt,
                            unsigned* __restrict__ fullmode) {
    int i = blockIdx.x * blockDim.x + threadIdx.x;
    if (i < 2 * MAXC)       out[i] = -1.0f;
    else if (i < 3 * MAXC)  out[i] = 0.0f;
    if (i < NBINS) { hist[i] = 0u; hist2[i] = 0u; }
    if (i == NBINS) *fullmode = 0u;
    if (i < NROWS) candcnt[i] = 0u;
}

// P1: flat branch-free scan. Double-buffered 4xfloat4 per thread; per
// quad-step one wave ballot -> 8B mask per 256 elements. No atomics, no
// LDS, no divergence in the hot loop.
__global__ __launch_bounds__(256) void scan_mask_kernel(
    const float* __restrict__ ms, unsigned long long* __restrict__ masks)
{
    const int tid = threadIdx.x;
    const int lane = tid & 63, wv = tid >> 6;
    const float4* m4 = (const float4*)ms;
    const int g = gridDim.x;

    float4 b0[4], b1[4];
    auto issue = [&](int t, float4* B) {
        const float4* p = m4 + (size_t)t * TILEQ + tid;
        #pragma unroll
        for (int k = 0; k < 4; ++k) B[k] = p[k * 256];
    };
    auto emit = [&](int t, const float4* B) {
        unsigned long long mk0 = __ballot((B[0].x > FCUT_LOG) | (B[0].y > FCUT_LOG) |
                                          (B[0].z > FCUT_LOG) | (B[0].w > FCUT_LOG));
        unsigned long long mk1 = __ballot((B[1].x > FCUT_LOG) | (B[1].y > FCUT_LOG) |
                                          (B[1].z > FCUT_LOG) | (B[1].w > FCUT_LOG));
        unsigned long long mk2 = __ballot((B[2].x > FCUT_LOG) | (B[2].y > FCUT_LOG) |
                                          (B[2].z > FCUT_LOG) | (B[2].w > FCUT_LOG));
        unsigned long long mk3 = __ballot((B[3].x > FCUT_LOG) | (B[3].y > FCUT_LOG) |
                                          (B[3].z > FCUT_LOG) | (B[3].w > FCUT_LOG));
        unsigned long long val = (lane & 2) ? ((lane & 1) ? mk3 : mk2)
                                            : ((lane & 1) ? mk1 : mk0);
        if (lane < 4)
            masks[(size_t)t * 16 + wv * 4 + lane] = val;   // idx = t*16+wv*4+k
    };

    int t = blockIdx.x;
    issue(t, b0);
    while (true) {
        int t1 = t + g;
        if (t1 < NTILES) issue(t1, b1);
        emit(t, b0);
        t = t1;
        if (t >= NTILES) break;
        int t2 = t + g;
        if (t2 < NTILES) issue(t2, b0);
        emit(t, b1);
        t = t2;
        if (t >= NTILES) break;
    }
}

// P2: expand masks (~450K hit elements). Exact bins -> hist; candidates
// -> per-row global buckets. Dustbin row/col filtered here.
__global__ __launch_bounds__(256) void expand_kernel(
    const float* __restrict__ ms, const float* __restrict__ refs,
    const float* __restrict__ srcs, const unsigned long long* __restrict__ masks,
    unsigned* __restrict__ hist, unsigned* __restrict__ candcnt,
    unsigned* __restrict__ cand_col, float* __restrict__ cand_v, int use_cand)
{
    __shared__ float t[NBINS];
    __shared__ unsigned sub[NBINS];
    int tid = threadIdx.x;
    if (tid == 0) fold_thresholds(t);
    if (tid < NBINS) sub[tid] = 0u;
    __syncthreads();

    for (int i = blockIdx.x * 256 + tid; i < NGROUPS; i += gridDim.x * 256) {
        unsigned long long mask = masks[i];
        if (!mask) continue;
        int tile = i >> 4, r = i & 15, w = r >> 2, k = r & 3;
        int quadBase = tile * TILEQ + k * 256 + w * 64;
        while (mask) {
            int b = __ffsll((long long)mask) - 1;
            mask &= mask - 1;
            int q = quadBase + b;
            float4 v4 = ((const float4*)ms)[q];
            int e0 = q * 4;
            #pragma unroll
            for (int j = 0; j < 4; ++j) {
                float m = (j == 0) ? v4.x : (j == 1) ? v4.y : (j == 2) ? v4.z : v4.w;
                if (!(m > FCUT_LOG)) continue;
                unsigned e = (unsigned)(e0 + j);
                unsigned row = e / 8193u;
                unsigned col = e - row * 8193u;
                if (row >= NROWS || col >= NCOLS) continue;   // dustbin
                float v = inner_val(m, refs[row], srcs[col]);
                atomicAdd(&sub[exact_bin(v, t)], 1u);
                if (use_cand) {
                    unsigned slot = atomicAdd(&candcnt[row], 1u);
                    if (slot < CAP) {
                        cand_col[(size_t)row * CAP + slot] = col;
                        cand_v[(size_t)row * CAP + slot]   = v;
                    }
                }
            }
        }
    }
    __syncthreads();
    if (tid < NBINS && sub[tid]) atomicAdd(&hist[tid], sub[tid]);
}

// Select threshold from exact bins 0..41; otherwise flag full fallback.
__global__ void mid_kernel(const unsigned* __restrict__ hist,
                           float* __restrict__ thres, unsigned* __restrict__ nstar,
                           unsigned* __restrict__ fullmode) {
    int tid = threadIdx.x;   // 64
    unsigned cum = hist[tid];
    #pragma unroll
    for (int off = 1; off < 64; off <<= 1) {
        unsigned u = __shfl_up(cum, off);
        if (tid >= off) cum += u;
    }
    unsigned long long mk = __ballot(cum >= (unsigned)KCORR);
    if (tid == 0) {
        int nsel = mk ? (int)(__ffsll((long long)mk) - 1) : NBINS;
        if (nsel <= 41) {
            float tv = 0.5f;
            for (int n = 0; n < nsel; ++n) tv = tv - 0.01f;
            *thres = tv; *nstar = (unsigned)nsel; *fullmode = 0u;
        } else {
            *fullmode = 1u; *nstar = 63u; *thres = -1e30f;
        }
    }
}

// Dormant: exact full histogram (all elements, all bins) when fullmode.
__global__ __launch_bounds__(256) void fb_hist_kernel(
    const float* __restrict__ ms, const float* __restrict__ refs,
    const float* __restrict__ srcs, const unsigned* __restrict__ fullmode,
    unsigned* __restrict__ hist2)
{
    if (*fullmode == 0u) return;
    __shared__ float t[NBINS];
    __shared__ unsigned sub[64 * 65];
    int tid = threadIdx.x, lane = tid & 63;
    if (tid == 0) fold_thresholds(t);
    for (int i = tid; i < 64 * 65; i += 256) sub[i] = 0u;
    __syncthreads();
    unsigned* mysub = sub + lane * 65;
    for (int q = blockIdx.x * 256 + tid; q < NQUAD; q += gridDim.x * 256) {
        float4 v4 = ((const float4*)ms)[q];
        int e0 = q * 4;
        #pragma unroll
        for (int j = 0; j < 4; ++j) {
            float m = (j == 0) ? v4.x : (j == 1) ? v4.y : (j == 2) ? v4.z : v4.w;
            unsigned e = (unsigned)(e0 + j);
            unsigned row = e / 8193u;
            unsigned col = e - row * 8193u;
            if (row >= NROWS || col >= NCOLS) continue;
            float v = inner_val(m, refs[row], srcs[col]);
            atomicAdd(&mysub[exact_bin(v, t)], 1u);
        }
    }
    __syncthreads();
    if (tid < 64) {
        unsigned s = 0;
        for (int c = 0; c < 64; ++c) s += sub[c * 65 + tid];
        if (s) atomicAdd(&hist2[tid], s);
    }
}

// Dormant: exact re-selection from hist2.
__global__ void mid2_kernel(const unsigned* __restrict__ hist2,
                            const unsigned* __restrict__ fullmode,
                            float* __restrict__ thres, unsigned* __restrict__ nstar) {
    if (*fullmode == 0u) return;
    int tid = threadIdx.x;
    unsigned cum = hist2[tid];
    #pragma unroll
    for (int off = 1; off < 64; off <<= 1) {
        unsigned u = __shfl_up(cum, off);
        if (tid >= off) cum += u;
    }
    unsigned long long mk = __ballot(cum >= (unsigned)KCORR);
    if (tid == 0) {
        int nsel = mk ? (int)(__ffsll((long long)mk) - 1) : (NBINS - 1);
        float tv = 0.5f;
        for (int n = 0; n < nsel; ++n) tv = tv - 0.01f;
        *thres = tv; *nstar = (unsigned)nsel;
    }
}

// Row counts from candidates (normal path). One wave per row.
__global__ __launch_bounds__(256) void rowcnt_kernel(
    const float* __restrict__ ms, const float* __restrict__ refs,
    const float* __restrict__ srcs, const float* __restrict__ thresp,
    const unsigned* __restrict__ fullmode, const unsigned* __restrict__ candcnt,
    const float* __restrict__ cand_v, unsigned* __restrict__ rowcnt, int use_cand)
{
    if (!use_cand || *fullmode != 0u) return;
    int tid = threadIdx.x, wv = tid >> 6, lane = tid & 63;
    int row = blockIdx.x * 4 + wv;
    float th = *thresp;
    unsigned C = candcnt[row];
    unsigned c = 0;
    if (C <= CAP) {
        const float* cv = cand_v + (size_t)row * CAP;
        for (unsigned i = lane; i < C; i += 64) c += (cv[i] > th) ? 1u : 0u;
    } else {   // bucket overflow: exact full row scan
        float rr = refs[row];
        const float* mrow = ms + (size_t)row * LDIM;
        for (int col = lane; col < NCOLS; col += 64)
            c += (inner_val(mrow[col], rr, srcs[col]) > th) ? 1u : 0u;
    }
    #pragma unroll
    for (int off = 32; off > 0; off >>= 1) c += __shfl_down(c, off);
    if (lane == 0) rowcnt[row] = c;
}

// Dormant: full recount of every row when fullmode (or no candidate ws).
__global__ __launch_bounds__(256) void count2_kernel(
    const float* __restrict__ ms, const float* __restrict__ refs,
    const float* __restrict__ srcs, const float* __restrict__ thresp,
    const unsigned* __restrict__ fullmode, unsigned* __restrict__ rowcnt,
    int use_cand)
{
    if (use_cand && *fullmode == 0u) return;
    __shared__ unsigned tot;
    float th = *thresp;
    for (int r4 = 0; r4 < 4; ++r4) {
        int row = blockIdx.x * 4 + r4;
        if (threadIdx.x == 0) tot = 0;
        __syncthreads();
        float rr = refs[row];
        const float* mrow = ms + (size_t)row * LDIM;
        unsigned c = 0;
        for (int col = threadIdx.x; col < NCOLS; col += 256)
            c += (inner_val(mrow[col], rr, srcs[col]) > th) ? 1u : 0u;
        atomicAdd(&tot, c);
        __syncthreads();
        if (threadIdx.x == 0) rowcnt[row] = tot;
        __syncthreads();
    }
}

// Exclusive prefix over 8192 row counts (always runs).
__global__ __launch_bounds__(1024) void scan_kernel(
    const unsigned* __restrict__ rowcnt, unsigned* __restrict__ rowoff)
{
    __shared__ unsigned ssum[1024];
    int tid = threadIdx.x;
    int r0 = tid * 8;
    unsigned c[8], s = 0;
    #pragma unroll
    for (int k = 0; k < 8; ++k) { c[k] = rowcnt[r0 + k]; s += c[k]; }
    ssum[tid] = s;
    __syncthreads();
    for (int off = 1; off < 1024; off <<= 1) {
        unsigned v = (tid >= off) ? ssum[tid - off] : 0u;
        __syncthreads();
        ssum[tid] += v;
        __syncthreads();
    }
    unsigned excl = ssum[tid] - s;
    #pragma unroll
    for (int k = 0; k < 8; ++k) { rowoff[r0 + k] = excl; excl += c[k]; }
    if (tid == 1023) rowoff[NROWS] = excl;
}

// Write: candidate path filters+ranks (row-major order restored by col
// rank; candidates may arrive unordered). Full-scan per row otherwise.
__global__ __launch_bounds__(256) void cwrite_kernel(
    const float* __restrict__ ms, const float* __restrict__ refs,
    const float* __restrict__ srcs, const float* __restrict__ thresp,
    const unsigned* __restrict__ fullmode, const unsigned* __restrict__ rowoff,
    const unsigned* __restrict__ candcnt, const unsigned* __restrict__ cand_col,
    const float* __restrict__ cand_v, float* __restrict__ out, int use_cand)
{
    __shared__ unsigned s_col[4][64];
    __shared__ float    s_val[4][64];
    int tid = threadIdx.x, wv = tid >> 6, lane = tid & 63;
    int row = blockIdx.x * 4 + wv;
    unsigned base = rowoff[row], next = rowoff[row + 1];
    if (base == next || base >= MAXC) return;   // wave-uniform exit
    float th = *thresp;
    unsigned k = next - base;
    bool full = (!use_cand) || (*fullmode != 0u) || (candcnt[row] > CAP) || (k > 64);

    if (!full) {
        unsigned C = candcnt[row];
        const unsigned* cc = cand_col + (size_t)row * CAP;
        const float*    cv = cand_v  + (size_t)row * CAP;
        unsigned nrun = 0;
        for (unsigned c0 = 0; c0 < C; c0 += 64) {
            unsigned i = c0 + lane;
            bool sel = false; unsigned col = 0; float v = 0.f;
            if (i < C) { col = cc[i]; v = cv[i]; sel = (v > th); }
            unsigned long long mk = __ballot(sel);
            if (sel) {
                unsigned idx = nrun + (unsigned)__popcll(mk & ((1ull << lane) - 1ull));
                if (idx < 64) { s_col[wv][idx] = col; s_val[wv][idx] = v; }
            }
            nrun += (unsigned)__popcll(mk);
        }
        __builtin_amdgcn_s_waitcnt(0);       // drain LDS writes
        __builtin_amdgcn_wave_barrier();     // block compiler reordering
        unsigned kk = (nrun < k) ? nrun : k;
        if (kk > 64) kk = 64;
        if (lane < (int)kk) {
            unsigned mycol = s_col[wv][lane];
            float    myval = s_val[wv][lane];
            unsigned rank = 0;
            for (unsigned j = 0; j < kk; ++j)
                rank += (s_col[wv][j] < mycol) ? 1u : 0u;
            unsigned pos = base + rank;
            if (pos < MAXC) {
                out[pos]            = (float)row;
                out[MAXC + pos]     = (float)mycol;
                out[2 * MAXC + pos] = myval;
            }
        }
        return;
    }

    // full-row ordered ballot scan (exact thres; correct for any input)
    float rr = refs[row];
    const float* mrow = ms + (size_t)row * LDIM;
    unsigned running = base;
    for (int c0 = 0; c0 < NCOLS && running < next && running < MAXC; c0 += 64) {
        int col = c0 + lane;
        float v = inner_val(mrow[col], rr, srcs[col]);
        bool pred = v > th;
        unsigned long long mk = __ballot(pred);
        if (pred) {
            unsigned pos = running + (unsigned)__popcll(mk & ((1ull << lane) - 1ull));
            if (pos < MAXC) {
                out[pos]            = (float)row;
                out[MAXC + pos]     = (float)col;
                out[2 * MAXC + pos] = v;
            }
        }
        running += (unsigned)__popcll(mk);
    }
}

extern "C" void kernel_launch(void* const* d_in, const int* in_sizes, int n_in,
                              void* d_out, int out_size, void* d_ws, size_t ws_size,
                              hipStream_t stream) {
    const float* ms  = (const float*)d_in[0];
    const float* ref = (const float*)d_in[1];
    const float* src = (const float*)d_in[2];
    float* out = (float*)d_out;

    char* w = (char*)d_ws;
    unsigned* hist     = (unsigned*)(w);          // 64 u32
    unsigned* hist2    = (unsigned*)(w + 256);    // 64 u32
    float*    thres    = (float*)(w + 512);
    unsigned* nstar    = (unsigned*)(w + 516);
    unsigned* fullmode = (unsigned*)(w + 520);
    unsigned* rowcnt   = (unsigned*)(w + 1024);               // 8192 u32
    unsigned* rowoff   = (unsigned*)(w + 1024 + NROWS * 4);   // 8193 u32
    size_t cc_off = (1024 + (size_t)NROWS * 4 + (size_t)(NROWS + 1) * 4 + 255) & ~(size_t)255;
    unsigned* candcnt = (unsigned*)(w + cc_off);              // 8192 u32
    size_t mk_off  = cc_off + (size_t)NROWS * 4;
    unsigned long long* masks = (unsigned long long*)(w + mk_off);  // 2.1 MB
    size_t col_off = mk_off + (size_t)NGROUPS * 8;
    unsigned* cand_col = (unsigned*)(w + col_off);            // 6.3 MB
    size_t cv_off  = col_off + (size_t)NROWS * CAP * 4;
    float* cand_v  = (float*)(w + cv_off);                    // 6.3 MB
    size_t end_off = cv_off + (size_t)NROWS * CAP * 4;        // ~16.8 MB

    int use_mask = (ws_size >= col_off) ? 1 : 0;
    int use_cand = (ws_size >= end_off) ? 1 : 0;

    init_kernel<<<96, 256, 0, stream>>>(out, hist, hist2, candcnt, fullmode);
    if (use_mask) {
        scan_mask_kernel<<<2048, 256, 0, stream>>>(ms, masks);
        expand_kernel<<<1024, 256, 0, stream>>>(ms, ref, src, masks, hist,
                                                candcnt, cand_col, cand_v, use_cand);
    }
    // if !use_mask: hist stays 0 -> mid flags fullmode -> exact fb path
    mid_kernel<<<1, 64, 0, stream>>>(hist, thres, nstar, fullmode);
    fb_hist_kernel<<<2048, 256, 0, stream>>>(ms, ref, src, fullmode, hist2);
    mid2_kernel<<<1, 64, 0, stream>>>(hist2, fullmode, thres, nstar);
    rowcnt_kernel<<<NROWS / 4, 256, 0, stream>>>(ms, ref, src, thres, fullmode,
                                                 candcnt, cand_v, rowcnt, use_cand);
    count2_kernel<<<NROWS / 4, 256, 0, stream>>>(ms, ref, src, thres, fullmode,
                                                 rowcnt, use_cand);
    scan_kernel<<<1, 1024, 0, stream>>>(rowcnt, rowoff);
    cwrite_kernel<<<NROWS / 4, 256, 0, stream>>>(ms, ref, src, thres, fullmode,
                                                 rowoff, candcnt, cand_col,
                                                 cand_v, out, use_cand);
}

// Round 8
// 426.586 us; speedup vs baseline: 1.0104x; 1.0104x over previous
//
#include <hip/hip_runtime.h>

#define NROWS 8192
#define NCOLS 8192
#define LDIM  8193          // matching_scores row stride
#define NBINS 64
#define KCORR 2048
#define MAXC  8192
#define CAP   192           // per-row candidate bucket (mean ~55, sd ~7.5)
#define BCAP  448           // per-block pair list (mean ~226, sd ~15)
// Fast cut: v = exp(m)*p < exp(m) <= 0.08 < t41 (~0.09) since p=rr*sc<1.
// Bins 0..41 exact from pushed elements alone; expected crossing n* ~ 33.
#define FCUT_LOG (-2.5257286443082556f)   // ln(0.08)

#define NQUAD   16781312    // floor(8193*8193/4); leftover elem = dustbin corner
#define TOTW    8192        // 2048 blocks * 4 waves
#define QSTRIDE 524288      // TOTW * 64 quads per step
// steps: 32 full (covers 16777216 quads) + tail step for waves W<64 (4096 quads)

__device__ __forceinline__ float inner_val(float m, float rr, float sc) {
    float p = rr * sc;
    return expf(m) * p;      // EXACTLY the reference expression
}

__device__ __forceinline__ void fold_thresholds(float* t) {
    float tv = 0.5f;
    for (int n = 0; n < NBINS; ++n) { t[n] = tv; tv = tv - 0.01f; }
}

// exact bin = #{n : t[n] >= v}: arithmetic guess + short verify walk
__device__ __forceinline__ int exact_bin(float v, const float* t) {
    int g = (int)floorf((0.5f - v) * 100.0f) + 1;
    g = (g < 0) ? 0 : ((g > NBINS) ? NBINS : g);
    while (g < NBINS && t[g] >= v) ++g;
    while (g > 0 && t[g - 1] < v) --g;
    return (g > 63) ? 63 : g;
}

__device__ __forceinline__ void gl2lds16(const void* g, void* l) {
    __builtin_amdgcn_global_load_lds(
        (const __attribute__((address_space(1))) void*)g,
        (__attribute__((address_space(3))) void*)l, 16, 0, 0);
}

__global__ void init_kernel(float* __restrict__ out, unsigned* __restrict__ hist,
                            unsigned* __restrict__ hist2,
                            unsigned* __restrict__ candcnt,
                            unsigned* __restrict__ fullmode,
                            unsigned* __restrict__ ovfl) {
    int i = blockIdx.x * blockDim.x + threadIdx.x;
    if (i < 2 * MAXC)       out[i] = -1.0f;
    else if (i < 3 * MAXC)  out[i] = 0.0f;
    if (i < NBINS) { hist[i] = 0u; hist2[i] = 0u; }
    if (i == NBINS) { *fullmode = 0u; *ovfl = 0u; }
    if (i < NROWS) candcnt[i] = 0u;
}

// DMA scan: per-wave 8-slot LDS ring fed by global_load_lds (7 in flight),
// explicit vmcnt waits, NO barriers in the steady loop. Hits push (elem,m)
// to a block LDS list; epilogue bins exactly + emits per-row candidates.
__global__ __launch_bounds__(256) void dscan_kernel(
    const float* __restrict__ ms, const float* __restrict__ refs,
    const float* __restrict__ srcs, unsigned* __restrict__ hist,
    unsigned* __restrict__ candcnt, unsigned* __restrict__ cand_col,
    float* __restrict__ cand_v, unsigned* __restrict__ ovfl, int use_cand)
{
    __shared__ float ring[4 * 8 * 256];     // 4 waves * 8 slots * 1 KB = 32 KB
    __shared__ float t[NBINS];
    __shared__ unsigned sub[NBINS];
    __shared__ unsigned s_cnt;
    __shared__ uint2 pairs[BCAP];           // 3.5 KB

    int tid = threadIdx.x, wv = tid >> 6, lane = tid & 63;
    if (tid == 0) { fold_thresholds(t); s_cnt = 0u; }
    if (tid < NBINS) sub[tid] = 0u;
    __syncthreads();

    int W = blockIdx.x * 4 + wv;            // 0..8191
    const float4* m4 = (const float4*)ms;
    float* myring = &ring[wv * (8 * 256)];  // wave-private 8 KB
    // blocks 0..15 (W<64) uniformly take the tail step
    int nsteps = 32 + ((W < 64) ? 1 : 0);

    auto pushp = [&](unsigned e, float m) {
        unsigned slot = atomicAdd(&s_cnt, 1u);
        if (slot < BCAP) pairs[slot] = make_uint2(e, __float_as_uint(m));
    };
    auto issue = [&](int s) {
        // global src: quad s*QSTRIDE + W*64 + lane (16B aligned);
        // LDS dst: wave-uniform slot base, HW adds lane*16
        gl2lds16(m4 + (size_t)s * QSTRIDE + (size_t)W * 64 + lane,
                 &myring[(s & 7) * 256]);
    };

    #pragma unroll
    for (int s = 0; s < 7; ++s) issue(s);   // 7 outstanding
    for (int s = 0; s < nsteps; ++s) {
        if (s + 7 < nsteps) {
            // slot (s+7)&7 == (s-1)&7: consumed last iter; its ds_read was
            // drained (lgkmcnt) before its values were used -> safe to refill
            issue(s + 7);
            asm volatile("s_waitcnt vmcnt(7)" ::: "memory");   // slot s done
        } else {
            asm volatile("s_waitcnt vmcnt(0)" ::: "memory");   // tail drain
        }
        float4 q = *(const float4*)&myring[(s & 7) * 256 + lane * 4];
        bool a0 = q.x > FCUT_LOG, a1 = q.y > FCUT_LOG;
        bool a2 = q.z > FCUT_LOG, a3 = q.w > FCUT_LOG;
        if (a0 | a1 | a2 | a3) {            // ~17% of lanes' quads never hit
            unsigned e0 = ((unsigned)s * QSTRIDE + (unsigned)W * 64 + (unsigned)lane) * 4u;
            if (a0) pushp(e0 + 0, q.x);
            if (a1) pushp(e0 + 1, q.y);
            if (a2) pushp(e0 + 2, q.z);
            if (a3) pushp(e0 + 3, q.w);
        }
    }
    __syncthreads();

    unsigned C = s_cnt;
    unsigned Cc = (C < BCAP) ? C : BCAP;
    for (unsigned i = tid; i < Cc; i += 256) {
        uint2 pr = pairs[i];
        unsigned e = pr.x;
        float m = __uint_as_float(pr.y);
        unsigned row = e / 8193u;           // magic-mul
        unsigned col = e - row * 8193u;
        if (row < NROWS && col < NCOLS) {   // dustbin filtered here
            float v = inner_val(m, refs[row], srcs[col]);
            atomicAdd(&sub[exact_bin(v, t)], 1u);
            if (use_cand) {
                unsigned slot = atomicAdd(&candcnt[row], 1u);
                if (slot < CAP) {
                    cand_col[(size_t)row * CAP + slot] = col;
                    cand_v[(size_t)row * CAP + slot]   = v;
                }
            }
        }
    }
    if (tid == 0 && C > BCAP) atomicOr(ovfl, 1u);   // hist corrupt -> fullmode
    __syncthreads();
    if (tid < NBINS && sub[tid]) atomicAdd(&hist[tid], sub[tid]);
}

// Threshold from exact bins 0..41; otherwise flag full fallback.
__global__ void mid_kernel(const unsigned* __restrict__ hist,
                           const unsigned* __restrict__ ovfl,
                           float* __restrict__ thres, unsigned* __restrict__ nstar,
                           unsigned* __restrict__ fullmode) {
    int tid = threadIdx.x;   // 64
    unsigned cum = hist[tid];
    #pragma unroll
    for (int off = 1; off < 64; off <<= 1) {
        unsigned u = __shfl_up(cum, off);
        if (tid >= off) cum += u;
    }
    unsigned long long mk = __ballot(cum >= (unsigned)KCORR);
    if (tid == 0) {
        int nsel = mk ? (int)(__ffsll((long long)mk) - 1) : NBINS;
        if (nsel <= 41 && *ovfl == 0u) {
            float tv = 0.5f;                  // replicate the float fold
            for (int n = 0; n < nsel; ++n) tv = tv - 0.01f;
            *thres = tv; *nstar = (unsigned)nsel; *fullmode = 0u;
        } else {
            *fullmode = 1u; *nstar = 63u; *thres = -1e30f;
        }
    }
}

// Dormant: exact full histogram when fullmode.
__global__ __launch_bounds__(256) void fb_hist_kernel(
    const float* __restrict__ ms, const float* __restrict__ refs,
    const float* __restrict__ srcs, const unsigned* __restrict__ fullmode,
    unsigned* __restrict__ hist2)
{
    if (*fullmode == 0u) return;
    __shared__ float t[NBINS];
    __shared__ unsigned sub[64 * 65];
    int tid = threadIdx.x, lane = tid & 63;
    if (tid == 0) fold_thresholds(t);
    for (int i = tid; i < 64 * 65; i += 256) sub[i] = 0u;
    __syncthreads();
    unsigned* mysub = sub + lane * 65;
    for (int q = blockIdx.x * 256 + tid; q < NQUAD; q += gridDim.x * 256) {
        float4 v4 = ((const float4*)ms)[q];
        int e0 = q * 4;
        #pragma unroll
        for (int j = 0; j < 4; ++j) {
            float m = (j == 0) ? v4.x : (j == 1) ? v4.y : (j == 2) ? v4.z : v4.w;
            unsigned e = (unsigned)(e0 + j);
            unsigned row = e / 8193u;
            unsigned col = e - row * 8193u;
            if (row >= NROWS || col >= NCOLS) continue;
            float v = inner_val(m, refs[row], srcs[col]);
            atomicAdd(&mysub[exact_bin(v, t)], 1u);
        }
    }
    __syncthreads();
    if (tid < 64) {
        unsigned s = 0;
        for (int c = 0; c < 64; ++c) s += sub[c * 65 + tid];
        if (s) atomicAdd(&hist2[tid], s);
    }
}

// Dormant: exact re-selection from hist2.
__global__ void mid2_kernel(const unsigned* __restrict__ hist2,
                            const unsigned* __restrict__ fullmode,
                            float* __restrict__ thres, unsigned* __restrict__ nstar) {
    if (*fullmode == 0u) return;
    int tid = threadIdx.x;
    unsigned cum = hist2[tid];
    #pragma unroll
    for (int off = 1; off < 64; off <<= 1) {
        unsigned u = __shfl_up(cum, off);
        if (tid >= off) cum += u;
    }
    unsigned long long mk = __ballot(cum >= (unsigned)KCORR);
    if (tid == 0) {
        int nsel = mk ? (int)(__ffsll((long long)mk) - 1) : (NBINS - 1);
        float tv = 0.5f;
        for (int n = 0; n < nsel; ++n) tv = tv - 0.01f;
        *thres = tv; *nstar = (unsigned)nsel;
    }
}

// Row counts from candidates (normal path). One wave per row.
__global__ __launch_bounds__(256) void rowcnt_kernel(
    const float* __restrict__ ms, const float* __restrict__ refs,
    const float* __restrict__ srcs, const float* __restrict__ thresp,
    const unsigned* __restrict__ fullmode, const unsigned* __restrict__ candcnt,
    const float* __restrict__ cand_v, unsigned* __restrict__ rowcnt, int use_cand)
{
    if (!use_cand || *fullmode != 0u) return;
    int tid = threadIdx.x, wv = tid >> 6, lane = tid & 63;
    int row = blockIdx.x * 4 + wv;
    float th = *thresp;
    unsigned C = candcnt[row];
    unsigned c = 0;
    if (C <= CAP) {
        const float* cv = cand_v + (size_t)row * CAP;
        for (unsigned i = lane; i < C; i += 64) c += (cv[i] > th) ? 1u : 0u;
    } else {   // per-row bucket overflow: exact full row scan
        float rr = refs[row];
        const float* mrow = ms + (size_t)row * LDIM;
        for (int col = lane; col < NCOLS; col += 64)
            c += (inner_val(mrow[col], rr, srcs[col]) > th) ? 1u : 0u;
    }
    #pragma unroll
    for (int off = 32; off > 0; off >>= 1) c += __shfl_down(c, off);
    if (lane == 0) rowcnt[row] = c;
}

// Dormant: full recount of every row when fullmode (or no candidate ws).
__global__ __launch_bounds__(256) void count2_kernel(
    const float* __restrict__ ms, const float* __restrict__ refs,
    const float* __restrict__ srcs, const float* __restrict__ thresp,
    const unsigned* __restrict__ fullmode, unsigned* __restrict__ rowcnt,
    int use_cand)
{
    if (use_cand && *fullmode == 0u) return;
    __shared__ unsigned tot;
    float th = *thresp;
    for (int r4 = 0; r4 < 4; ++r4) {
        int row = blockIdx.x * 4 + r4;
        if (threadIdx.x == 0) tot = 0;
        __syncthreads();
        float rr = refs[row];
        const float* mrow = ms + (size_t)row * LDIM;
        unsigned c = 0;
        for (int col = threadIdx.x; col < NCOLS; col += 256)
            c += (inner_val(mrow[col], rr, srcs[col]) > th) ? 1u : 0u;
        atomicAdd(&tot, c);
        __syncthreads();
        if (threadIdx.x == 0) rowcnt[row] = tot;
        __syncthreads();
    }
}

// Exclusive prefix over 8192 row counts (always runs).
__global__ __launch_bounds__(1024) void scan_kernel(
    const unsigned* __restrict__ rowcnt, unsigned* __restrict__ rowoff)
{
    __shared__ unsigned ssum[1024];
    int tid = threadIdx.x;
    int r0 = tid * 8;
    unsigned c[8], s = 0;
    #pragma unroll
    for (int k = 0; k < 8; ++k) { c[k] = rowcnt[r0 + k]; s += c[k]; }
    ssum[tid] = s;
    __syncthreads();
    for (int off = 1; off < 1024; off <<= 1) {
        unsigned v = (tid >= off) ? ssum[tid - off] : 0u;
        __syncthreads();
        ssum[tid] += v;
        __syncthreads();
    }
    unsigned excl = ssum[tid] - s;
    #pragma unroll
    for (int k = 0; k < 8; ++k) { rowoff[r0 + k] = excl; excl += c[k]; }
    if (tid == 1023) rowoff[NROWS] = excl;
}

// Write: candidate path filters+ranks (row-major order via col rank);
// full-scan per row otherwise.
__global__ __launch_bounds__(256) void cwrite_kernel(
    const float* __restrict__ ms, const float* __restrict__ refs,
    const float* __restrict__ srcs, const float* __restrict__ thresp,
    const unsigned* __restrict__ fullmode, const unsigned* __restrict__ rowoff,
    const unsigned* __restrict__ candcnt, const unsigned* __restrict__ cand_col,
    const float* __restrict__ cand_v, float* __restrict__ out, int use_cand)
{
    __shared__ unsigned s_col[4][64];
    __shared__ float    s_val[4][64];
    int tid = threadIdx.x, wv = tid >> 6, lane = tid & 63;
    int row = blockIdx.x * 4 + wv;
    unsigned base = rowoff[row], next = rowoff[row + 1];
    if (base == next || base >= MAXC) return;   // wave-uniform exit
    float th = *thresp;
    unsigned k = next - base;
    bool full = (!use_cand) || (*fullmode != 0u) || (candcnt[row] > CAP) || (k > 64);

    if (!full) {
        unsigned C = candcnt[row];
        const unsigned* cc = cand_col + (size_t)row * CAP;
        const float*    cv = cand_v  + (size_t)row * CAP;
        unsigned nrun = 0;
        for (unsigned c0 = 0; c0 < C; c0 += 64) {
            unsigned i = c0 + lane;
            bool sel = false; unsigned col = 0; float v = 0.f;
            if (i < C) { col = cc[i]; v = cv[i]; sel = (v > th); }
            unsigned long long mk = __ballot(sel);
            if (sel) {
                unsigned idx = nrun + (unsigned)__popcll(mk & ((1ull << lane) - 1ull));
                if (idx < 64) { s_col[wv][idx] = col; s_val[wv][idx] = v; }
            }
            nrun += (unsigned)__popcll(mk);
        }
        __builtin_amdgcn_s_waitcnt(0);       // drain LDS writes
        __builtin_amdgcn_wave_barrier();     // block compiler reordering
        unsigned kk = (nrun < k) ? nrun : k;
        if (kk > 64) kk = 64;
        if (lane < (int)kk) {
            unsigned mycol = s_col[wv][lane];
            float    myval = s_val[wv][lane];
            unsigned rank = 0;
            for (unsigned j = 0; j < kk; ++j)
                rank += (s_col[wv][j] < mycol) ? 1u : 0u;
            unsigned pos = base + rank;
            if (pos < MAXC) {
                out[pos]            = (float)row;
                out[MAXC + pos]     = (float)mycol;
                out[2 * MAXC + pos] = myval;
            }
        }
        return;
    }

    // full-row ordered ballot scan (exact thres; correct for any input)
    float rr = refs[row];
    const float* mrow = ms + (size_t)row * LDIM;
    unsigned running = base;
    for (int c0 = 0; c0 < NCOLS && running < next && running < MAXC; c0 += 64) {
        int col = c0 + lane;
        float v = inner_val(mrow[col], rr, srcs[col]);
        bool pred = v > th;
        unsigned long long mk = __ballot(pred);
        if (pred) {
            unsigned pos = running + (unsigned)__popcll(mk & ((1ull << lane) - 1ull));
            if (pos < MAXC) {
                out[pos]            = (float)row;
                out[MAXC + pos]     = (float)col;
                out[2 * MAXC + pos] = v;
            }
        }
        running += (unsigned)__popcll(mk);
    }
}

extern "C" void kernel_launch(void* const* d_in, const int* in_sizes, int n_in,
                              void* d_out, int out_size, void* d_ws, size_t ws_size,
                              hipStream_t stream) {
    const float* ms  = (const float*)d_in[0];
    const float* ref = (const float*)d_in[1];
    const float* src = (const float*)d_in[2];
    float* out = (float*)d_out;

    char* w = (char*)d_ws;
    unsigned* hist     = (unsigned*)(w);          // 64 u32
    unsigned* hist2    = (unsigned*)(w + 256);    // 64 u32
    float*    thres    = (float*)(w + 512);
    unsigned* nstar    = (unsigned*)(w + 516);
    unsigned* fullmode = (unsigned*)(w + 520);
    unsigned* ovfl     = (unsigned*)(w + 524);
    unsigned* rowcnt   = (unsigned*)(w + 1024);               // 8192 u32
    unsigned* rowoff   = (unsigned*)(w + 1024 + NROWS * 4);   // 8193 u32
    size_t cc_off = (1024 + (size_t)NROWS * 4 + (size_t)(NROWS + 1) * 4 + 255) & ~(size_t)255;
    unsigned* candcnt = (unsigned*)(w + cc_off);              // 8192 u32
    size_t col_off = cc_off + (size_t)NROWS * 4;
    unsigned* cand_col = (unsigned*)(w + col_off);            // 6.3 MB
    size_t cv_off  = col_off + (size_t)NROWS * CAP * 4;
    float* cand_v  = (float*)(w + cv_off);                    // 6.3 MB
    size_t end_off = cv_off + (size_t)NROWS * CAP * 4;        // ~12.7 MB

    int use_cand = (ws_size >= end_off) ? 1 : 0;

    init_kernel<<<96, 256, 0, stream>>>(out, hist, hist2, candcnt, fullmode, ovfl);
    dscan_kernel<<<2048, 256, 0, stream>>>(ms, ref, src, hist, candcnt,
                                           cand_col, cand_v, ovfl, use_cand);
    mid_kernel<<<1, 64, 0, stream>>>(hist, ovfl, thres, nstar, fullmode);
    fb_hist_kernel<<<2048, 256, 0, stream>>>(ms, ref, src, fullmode, hist2);
    mid2_kernel<<<1, 64, 0, stream>>>(hist2, fullmode, thres, nstar);
    rowcnt_kernel<<<NROWS / 4, 256, 0, stream>>>(ms, ref, src, thres, fullmode,
                                                 candcnt, cand_v, rowcnt, use_cand);
    count2_kernel<<<NROWS / 4, 256, 0, stream>>>(ms, ref, src, thres, fullmode,
                                                 rowcnt, use_cand);
    scan_kernel<<<1, 1024, 0, stream>>>(rowcnt, rowoff);
    cwrite_kernel<<<NROWS / 4, 256, 0, stream>>>(ms, ref, src, thres, fullmode,
                                                 rowoff, candcnt, cand_col,
                                                 cand_v, out, use_cand);
}